// Round 3
// baseline (182.633 us; speedup 1.0000x reference)
//
#include <hip/hip_runtime.h>
#include <math.h>

// Problem constants (B=2, N=M=2048, d_model=1024, m_bits=32, d_head=64)
#define DM 1024
#define NB 2048
#define MBITS 32
#define DH 64

typedef __attribute__((ext_vector_type(4))) float floatx4;
typedef __attribute__((ext_vector_type(8))) short shortx8;

__device__ __forceinline__ unsigned short f32_to_bf16(float f) {
    union { float f; unsigned u; } v; v.f = f;
    unsigned r = v.u + 0x7FFF + ((v.u >> 16) & 1);   // RNE
    return (unsigned short)(r >> 16);
}

// hi/lo truncation split of two f32 -> packed bf16x2 (el0 low, el1 high)
__device__ __forceinline__ void split2(float x0, float x1, unsigned& hp, unsigned& lp) {
    union { float f; unsigned u; } a, b; a.f = x0; b.f = x1;
    unsigned h0 = a.u & 0xFFFF0000u, h1 = b.u & 0xFFFF0000u;
    union { unsigned u; float f; } hf0, hf1; hf0.u = h0; hf1.u = h1;
    union { float f; unsigned u; } c, d;
    c.f = x0 - hf0.f;   // exact
    d.f = x1 - hf1.f;
    hp = (h0 >> 16) | h1;
    lp = (c.u >> 16) | (d.u & 0xFFFF0000u);
}

// ---------------------------------------------------------------------------
// W prep: pack Wq/Wk/Wv into MFMA B-frag order, bf16 hi/lo.
// Pair p: Wf[p*1024 + lane*8 + j] = hi, [+512] = lo.
//  p in [0,64): Wq  (kc32 = p>>1, ct = p&1,  C=32)
//  p in [64,128): Wk
//  p in [128,256): Wv (z = p-128: kc32 = z>>2, ct = z&3, C=64)
// B-frag: lane l holds B[k = kc32*32 + (l>>4)*8 + j][col = ct*16 + (l&15)].
// grid 64 x 256 (one wave per pair).
// ---------------------------------------------------------------------------
__global__ __launch_bounds__(256) void wprep_kernel(
    const float* __restrict__ Wq, const float* __restrict__ Wk,
    const float* __restrict__ Wv, unsigned short* __restrict__ Wf)
{
    int wv = blockIdx.x * 4 + (threadIdx.x >> 6);
    int l  = threadIdx.x & 63;
    const float* W; int C, kc32, ct;
    if (wv < 64)       { W = Wq; C = 32; kc32 = wv >> 1;  ct = wv & 1; }
    else if (wv < 128) { W = Wk; C = 32; int z = wv - 64;  kc32 = z >> 1; ct = z & 1; }
    else               { W = Wv; C = 64; int z = wv - 128; kc32 = z >> 2; ct = z & 3; }
    int k0 = kc32 * 32 + (l >> 4) * 8;
    int c  = ct * 16 + (l & 15);
    float x[8];
    #pragma unroll
    for (int j = 0; j < 8; ++j) x[j] = W[(size_t)(k0 + j) * C + c];
    unsigned hp[4], lp[4];
    #pragma unroll
    for (int j2 = 0; j2 < 4; ++j2) split2(x[2 * j2], x[2 * j2 + 1], hp[j2], lp[j2]);
    uint4 hv; hv.x = hp[0]; hv.y = hp[1]; hv.z = hp[2]; hv.w = hp[3];
    uint4 lv; lv.x = lp[0]; lv.y = lp[1]; lv.z = lp[2]; lv.w = lp[3];
    *(uint4*)&Wf[(size_t)wv * 1024 + l * 8]       = hv;
    *(uint4*)&Wf[(size_t)wv * 1024 + 512 + l * 8] = lv;
}

// ---------------------------------------------------------------------------
// Projections via MFMA with hi/lo 3-term product (effectively f32 precision).
// grid 768 x 64 (one wave per 16-row output tile; job = blockIdx.x>>8).
//  job 0: Qt = Q@Wq [4096][32] f32
//  job 1: Kt = K@Wk [4096][32] f32
//  job 2: VpT = (V@Wv)^T bf16 [b][h][j]
// ---------------------------------------------------------------------------
__global__ __launch_bounds__(64) void proj_mfma_kernel(
    const float* __restrict__ Q, const float* __restrict__ K, const float* __restrict__ V,
    const unsigned short* __restrict__ Wf,
    float* __restrict__ Qt, float* __restrict__ Kt, unsigned short* __restrict__ VpT)
{
    __shared__ unsigned short Xhi[16][72];   // [row][k], pad 72 (2-way banks, free)
    __shared__ unsigned short Xlo[16][72];

    int gb = blockIdx.x;
    int job = gb >> 8, tile = gb & 255;
    int r0 = tile * 16;
    const float* X = (job == 0) ? Q : (job == 1) ? K : V;
    int ntct  = (job == 2) ? 4 : 2;
    int pbase = job << 6;                    // 0, 64, 128
    int l = threadIdx.x;
    int lrow = l & 15, lq = l >> 4;

    floatx4 acc[4];
    #pragma unroll
    for (int i = 0; i < 4; ++i) acc[i] = (floatx4){0.f, 0.f, 0.f, 0.f};

    // prefetch chunk 0 (16 rows x 64 k f32)
    floatx4 g[4];
    #pragma unroll
    for (int q = 0; q < 4; ++q)
        g[q] = *(const floatx4*)&X[(size_t)(r0 + q * 4 + lq) * DM + lrow * 4];

    for (int c = 0; c < 16; ++c) {
        floatx4 gn[4];
        if (c < 15) {
            #pragma unroll
            for (int q = 0; q < 4; ++q)
                gn[q] = *(const floatx4*)&X[(size_t)(r0 + q * 4 + lq) * DM + (c + 1) * 64 + lrow * 4];
        }
        __syncthreads();
        #pragma unroll
        for (int q = 0; q < 4; ++q) {
            unsigned h01, l01, h23, l23;
            split2(g[q].x, g[q].y, h01, l01);
            split2(g[q].z, g[q].w, h23, l23);
            uint2 hh; hh.x = h01; hh.y = h23;
            uint2 ll; ll.x = l01; ll.y = l23;
            *(uint2*)&Xhi[q * 4 + lq][lrow * 4] = hh;
            *(uint2*)&Xlo[q * 4 + lq][lrow * 4] = ll;
        }
        __syncthreads();
        #pragma unroll
        for (int sub = 0; sub < 2; ++sub) {
            shortx8 ahi = *(const shortx8*)&Xhi[lrow][sub * 32 + lq * 8];
            shortx8 alo = *(const shortx8*)&Xlo[lrow][sub * 32 + lq * 8];
            int kc32 = c * 2 + sub;
            for (int ct = 0; ct < ntct; ++ct) {
                int p = pbase + kc32 * ntct + ct;
                const unsigned short* wp = &Wf[(size_t)p * 1024 + l * 8];
                shortx8 bhi = *(const shortx8*)wp;
                shortx8 blo = *(const shortx8*)(wp + 512);
                acc[ct] = __builtin_amdgcn_mfma_f32_16x16x32_bf16(ahi, bhi, acc[ct], 0, 0, 0);
                acc[ct] = __builtin_amdgcn_mfma_f32_16x16x32_bf16(ahi, blo, acc[ct], 0, 0, 0);
                acc[ct] = __builtin_amdgcn_mfma_f32_16x16x32_bf16(alo, bhi, acc[ct], 0, 0, 0);
            }
        }
        #pragma unroll
        for (int q = 0; q < 4; ++q) g[q] = gn[q];
    }

    // C/D layout: col = lane&15, row = (lane>>4)*4 + reg
    if (job < 2) {
        float* Y = (job == 0) ? Qt : Kt;
        #pragma unroll
        for (int ct = 0; ct < 2; ++ct)
            #pragma unroll
            for (int r = 0; r < 4; ++r)
                Y[(size_t)(r0 + lq * 4 + r) * MBITS + ct * 16 + lrow] = acc[ct][r];
    } else {
        #pragma unroll
        for (int ct = 0; ct < 4; ++ct)
            #pragma unroll
            for (int r = 0; r < 4; ++r) {
                int row = r0 + lq * 4 + r;
                int b = row >> 11, j = row & 2047;
                VpT[(size_t)b * (DH * NB) + (size_t)(ct * 16 + lrow) * NB + j] =
                    f32_to_bf16(acc[ct][r]);
            }
    }
}

// ---------------------------------------------------------------------------
// Score pass: tropical min-plus, unnormalized e -> ebuf, per-(row,jc) partials.
// grid (128, 8, 2) x 256. Block = 16 rows x 256 j, thread 4i x 4j.
// ET = ushort (bf16 ebuf in ws) or float (f32 ebuf in attn region, fallback).
// ---------------------------------------------------------------------------
template <typename ET>
__global__ __launch_bounds__(256) void trop_score_kernel(
    const float* __restrict__ Qt, const float* __restrict__ Kt,
    const float* __restrict__ temp, float* __restrict__ partial,
    ET* __restrict__ ebuf)
{
    __shared__ float Qs[16][36];
    __shared__ float Ks[256][36];

    int b  = blockIdx.z;
    int jc = blockIdx.y;
    int i0 = blockIdx.x * 16;
    int t  = threadIdx.x;
    int w  = t >> 6, l = t & 63;

    if (t < 128) {
        int row = t >> 3, k4 = t & 7;
        *(floatx4*)&Qs[row][k4 * 4] =
            *(const floatx4*)&Qt[(size_t)(b * NB + i0 + row) * MBITS + k4 * 4];
    }
    #pragma unroll
    for (int u = 0; u < 8; ++u) {
        int flat4 = u * 256 + t;
        int row = flat4 >> 3, k4 = flat4 & 7;
        *(floatx4*)&Ks[row][k4 * 4] =
            *(const floatx4*)&Kt[(size_t)(b * NB + jc * 256 + row) * MBITS + k4 * 4];
    }
    float tv = temp[0];
    float c2 = -(1.0f / log1pf(__expf(tv))) * 1.44269504088896340736f;
    __syncthreads();

    float m[4][4];
    #pragma unroll
    for (int ii = 0; ii < 4; ++ii)
        #pragma unroll
        for (int jj = 0; jj < 4; ++jj) m[ii][jj] = 1e30f;

    #pragma unroll
    for (int k4 = 0; k4 < 8; ++k4) {
        floatx4 q[4], kk[4];
        #pragma unroll
        for (int ii = 0; ii < 4; ++ii) q[ii] = *(const floatx4*)&Qs[w + 4 * ii][k4 * 4];
        #pragma unroll
        for (int jj = 0; jj < 4; ++jj) kk[jj] = *(const floatx4*)&Ks[l + 64 * jj][k4 * 4];
        #pragma unroll
        for (int ii = 0; ii < 4; ++ii)
            #pragma unroll
            for (int jj = 0; jj < 4; ++jj) {
                float a0 = q[ii].x + kk[jj].x;
                float a1 = q[ii].y + kk[jj].y;
                float a2 = q[ii].z + kk[jj].z;
                float a3 = q[ii].w + kk[jj].w;
                // min + min3-friendly shape
                m[ii][jj] = fminf(fminf(m[ii][jj], fminf(a0, a1)), fminf(a2, a3));
            }
    }

    float psum[4];
    #pragma unroll
    for (int ii = 0; ii < 4; ++ii) {
        int i = w + 4 * ii;
        float s = 0.f;
        #pragma unroll
        for (int jj = 0; jj < 4; ++jj) {
            int j = l + 64 * jj;
            float e = exp2f(c2 * m[ii][jj]);
            size_t idx = (size_t)(b * NB + i0 + i) * 2048 + jc * 256 + j;
            if (sizeof(ET) == 2) ebuf[idx] = (ET)f32_to_bf16(e);
            else                 ebuf[idx] = (ET)e;
            s += e;
        }
        psum[ii] = s;
    }

    #pragma unroll
    for (int ii = 0; ii < 4; ++ii) {
        float v = psum[ii];
        #pragma unroll
        for (int off = 1; off < 64; off <<= 1) v += __shfl_xor(v, off, 64);
        if (l == 0) partial[((size_t)b * NB + i0 + w + 4 * ii) * 8 + jc] = v;
    }
}

// ---------------------------------------------------------------------------
// Out pass: normalize -> attn (f32, written once in bf16-path), MFMA -> out.
// grid (128, 8, 2) x 256. EBF16: ebuf is bf16 scratch; else ebuf == attn (f32).
// ---------------------------------------------------------------------------
template <bool EBF16>
__global__ __launch_bounds__(256) void trop_out_kernel(
    const unsigned short* __restrict__ VpT, const float* __restrict__ partial,
    const void* __restrict__ ebuf_in, float* __restrict__ outp, float* __restrict__ attn)
{
    __shared__ unsigned short Vs[64][256];   // B-operand, XOR-swizzled 16B chunks
    __shared__ unsigned short Es[16][264];   // A-operand (unnormalized e, bf16)
    __shared__ float inv_s[16];

    int b  = blockIdx.z;
    int jc = blockIdx.y;
    int i0 = blockIdx.x * 16;
    int t  = threadIdx.x;
    int w  = t >> 6, l = t & 63;

    #pragma unroll
    for (int u = 0; u < 8; ++u) {
        int flat16 = u * 256 + t;
        int h = flat16 >> 5, c = flat16 & 31;
        uint4 g = *(const uint4*)&VpT[(size_t)b * (DH * NB) + (size_t)h * NB + jc * 256 + c * 8];
        *(uint4*)&Vs[h][(c ^ (h & 31)) * 8] = g;
    }
    if (t < 16) {
        float s = 0.f;
        #pragma unroll
        for (int p = 0; p < 8; ++p) s += partial[((size_t)b * NB + i0 + t) * 8 + p];
        inv_s[t] = 1.0f / s;
    }

    if (EBF16) {
        const unsigned short* eb = (const unsigned short*)ebuf_in;
        // stage bf16 e tile: 16 rows x 32 uint4 chunks
        #pragma unroll
        for (int u = 0; u < 2; ++u) {
            int flat = u * 256 + t;
            int row = flat >> 5, c = flat & 31;
            uint4 g = *(const uint4*)&eb[(size_t)(b * NB + i0 + row) * 2048 + jc * 256 + c * 8];
            *(uint4*)&Es[row][c * 8] = g;
        }
        __syncthreads();
        // write normalized attn f32 (once)
        int row = t >> 4, cb = (t & 15) * 16;
        float iv = inv_s[row];
        #pragma unroll
        for (int h8 = 0; h8 < 2; ++h8) {
            uint4 e8 = *(const uint4*)&Es[row][cb + h8 * 8];
            unsigned uu[4] = {e8.x, e8.y, e8.z, e8.w};
            float f[8];
            #pragma unroll
            for (int z = 0; z < 4; ++z) {
                union { unsigned u; float f; } v0, v1;
                v0.u = uu[z] << 16; v1.u = uu[z] & 0xFFFF0000u;
                f[2 * z] = v0.f * iv; f[2 * z + 1] = v1.f * iv;
            }
            size_t gidx = (size_t)(b * NB + i0 + row) * 2048 + jc * 256 + cb + h8 * 8;
            floatx4 o0; o0.x = f[0]; o0.y = f[1]; o0.z = f[2]; o0.w = f[3];
            floatx4 o1; o1.x = f[4]; o1.y = f[5]; o1.z = f[6]; o1.w = f[7];
            *(floatx4*)&attn[gidx]     = o0;
            *(floatx4*)&attn[gidx + 4] = o1;
        }
    } else {
        __syncthreads();
        // fallback: e is f32 in attn region; normalize in place + build Es
        #pragma unroll
        for (int u = 0; u < 4; ++u) {
            int flat4 = u * 256 + t;
            int row = flat4 >> 6, c4 = flat4 & 63;
            size_t g = (size_t)(b * NB + i0 + row) * 2048 + jc * 256 + c4 * 4;
            floatx4 e4 = *(const floatx4*)&attn[g];
            float iv = inv_s[row];
            unsigned u0 = (unsigned)f32_to_bf16(e4.x) | ((unsigned)f32_to_bf16(e4.y) << 16);
            unsigned u1 = (unsigned)f32_to_bf16(e4.z) | ((unsigned)f32_to_bf16(e4.w) << 16);
            uint2 pk; pk.x = u0; pk.y = u1;
            *(uint2*)&Es[row][c4 * 4] = pk;
            e4.x *= iv; e4.y *= iv; e4.z *= iv; e4.w *= iv;
            *(floatx4*)&attn[g] = e4;
        }
    }
    __syncthreads();

    floatx4 acc = {0.f, 0.f, 0.f, 0.f};
    #pragma unroll
    for (int kk = 0; kk < 8; ++kk) {
        int mrow = l & 15, q4 = l >> 4;
        shortx8 a = *(const shortx8*)&Es[mrow][kk * 32 + q4 * 8];
        int h = w * 16 + mrow;
        int c = kk * 4 + q4;
        shortx8 bf = *(const shortx8*)&Vs[h][(c ^ (h & 31)) * 8];
        acc = __builtin_amdgcn_mfma_f32_16x16x32_bf16(a, bf, acc, 0, 0, 0);
    }

    // C/D: col=lane&15 (h), row=(lane>>4)*4+reg (i); scale unnormalized acc
    #pragma unroll
    for (int r = 0; r < 4; ++r) {
        int irow = (l >> 4) * 4 + r;
        atomicAdd(&outp[(size_t)(b * NB + i0 + irow) * DH + w * 16 + (l & 15)],
                  acc[r] * inv_s[irow]);
    }
}

// ---------------------------------------------------------------------------
extern "C" void kernel_launch(void* const* d_in, const int* in_sizes, int n_in,
                              void* d_out, int out_size, void* d_ws, size_t ws_size,
                              hipStream_t stream) {
    (void)in_sizes; (void)n_in; (void)out_size;
    const float* Q    = (const float*)d_in[0];
    const float* K    = (const float*)d_in[1];
    const float* V    = (const float*)d_in[2];
    const float* Wq   = (const float*)d_in[3];
    const float* Wk   = (const float*)d_in[4];
    const float* Wv   = (const float*)d_in[5];
    const float* temp = (const float*)d_in[6];

    float* outp = (float*)d_out;                 // [2][2048][64]
    float* attn = outp + 2 * 2048 * 64;          // [2][2048][2048]

    char* ws = (char*)d_ws;
    float*          Qt      = (float*)(ws);                       // 512 KB
    float*          Kt      = (float*)(ws + 524288);              // 512 KB
    float*          partial = (float*)(ws + 1048576);             // 128 KB
    unsigned short* Wf      = (unsigned short*)(ws + 1179648);    // 512 KB
    unsigned short* VpT     = (unsigned short*)(ws + 1703936);    // 512 KB
    unsigned short* Ebuf    = (unsigned short*)(ws + 2228224);    // 32 MB (bf16 path)
    bool bf16path = ws_size >= (size_t)2228224 + 33554432;

    hipMemsetAsync(d_out, 0, 262144 * sizeof(float), stream);     // out accumulators

    wprep_kernel<<<64, 256, 0, stream>>>(Wq, Wk, Wv, Wf);
    proj_mfma_kernel<<<768, 64, 0, stream>>>(Q, K, V, Wf, Qt, Kt, VpT);

    if (bf16path) {
        trop_score_kernel<unsigned short><<<dim3(128, 8, 2), 256, 0, stream>>>(
            Qt, Kt, temp, partial, Ebuf);
        trop_out_kernel<true><<<dim3(128, 8, 2), 256, 0, stream>>>(
            VpT, partial, Ebuf, outp, attn);
    } else {
        trop_score_kernel<float><<<dim3(128, 8, 2), 256, 0, stream>>>(
            Qt, Kt, temp, partial, attn);
        trop_out_kernel<false><<<dim3(128, 8, 2), 256, 0, stream>>>(
            VpT, partial, attn, outp, attn);
    }
}

// Round 4
// 155.427 us; speedup vs baseline: 1.1750x; 1.1750x over previous
//
#include <hip/hip_runtime.h>
#include <math.h>

// Problem constants (B=2, N=M=2048, d_model=1024, m_bits=32, d_head=64)
#define DM 1024
#define NB 2048
#define MBITS 32
#define DH 64

typedef __attribute__((ext_vector_type(4))) float floatx4;
typedef __attribute__((ext_vector_type(8))) short shortx8;

__device__ __forceinline__ unsigned short f32_to_bf16(float f) {
    union { float f; unsigned u; } v; v.f = f;
    unsigned r = v.u + 0x7FFF + ((v.u >> 16) & 1);   // RNE
    return (unsigned short)(r >> 16);
}

// hi/lo truncation split of two f32 -> packed bf16x2 (el0 low, el1 high)
__device__ __forceinline__ void split2(float x0, float x1, unsigned& hp, unsigned& lp) {
    union { float f; unsigned u; } a, b; a.f = x0; b.f = x1;
    unsigned h0 = a.u & 0xFFFF0000u, h1 = b.u & 0xFFFF0000u;
    union { unsigned u; float f; } hf0, hf1; hf0.u = h0; hf1.u = h1;
    union { float f; unsigned u; } c, d;
    c.f = x0 - hf0.f;   // exact (Sterbenz)
    d.f = x1 - hf1.f;
    hp = (h0 >> 16) | h1;
    lp = (c.u >> 16) | (d.u & 0xFFFF0000u);
}

// ---------------------------------------------------------------------------
// W prep: pack Wq/Wk/Wv into MFMA B-frag order, bf16 hi/lo. (layout verified r3)
// Pair p: Wf[p*1024 + lane*8 + j] = hi, [+512] = lo.
//  p in [0,64): Wq (p = kc32*2 + ct); [64,128): Wk; [128,256): Wv (kc32*4+ct).
// B-frag: lane l holds B[k = kc32*32 + (l>>4)*8 + j][col = ct*16 + (l&15)].
// ---------------------------------------------------------------------------
__global__ __launch_bounds__(256) void wprep_kernel(
    const float* __restrict__ Wq, const float* __restrict__ Wk,
    const float* __restrict__ Wv, unsigned short* __restrict__ Wf)
{
    int wv = blockIdx.x * 4 + (threadIdx.x >> 6);
    int l  = threadIdx.x & 63;
    const float* W; int C, kc32, ct;
    if (wv < 64)       { W = Wq; C = 32; kc32 = wv >> 1;  ct = wv & 1; }
    else if (wv < 128) { W = Wk; C = 32; int z = wv - 64;  kc32 = z >> 1; ct = z & 1; }
    else               { W = Wv; C = 64; int z = wv - 128; kc32 = z >> 2; ct = z & 3; }
    int k0 = kc32 * 32 + (l >> 4) * 8;
    int c  = ct * 16 + (l & 15);
    float x[8];
    #pragma unroll
    for (int j = 0; j < 8; ++j) x[j] = W[(size_t)(k0 + j) * C + c];
    unsigned hp[4], lp[4];
    #pragma unroll
    for (int j2 = 0; j2 < 4; ++j2) split2(x[2 * j2], x[2 * j2 + 1], hp[j2], lp[j2]);
    uint4 hv; hv.x = hp[0]; hv.y = hp[1]; hv.z = hp[2]; hv.w = hp[3];
    uint4 lv; lv.x = lp[0]; lv.y = lp[1]; lv.z = lp[2]; lv.w = lp[3];
    *(uint4*)&Wf[(size_t)wv * 1024 + l * 8]       = hv;
    *(uint4*)&Wf[(size_t)wv * 1024 + 512 + l * 8] = lv;
}

// ---------------------------------------------------------------------------
// Projections v2: register-direct A-frags, split-K x4 across the block's 4
// waves, LDS cross-wave reduction. grid 768 x 256 (job = blockIdx.x>>8).
//  job 0: Qt = Q@Wq [4096][32] f32   job 1: Kt   job 2: VpT bf16 [b][h][j]
// Wave w: k in [w*256, w*256+256), 8 MFMA k-steps of 32. No barriers in loop.
// ---------------------------------------------------------------------------
__global__ __launch_bounds__(256) void proj_mfma2_kernel(
    const float* __restrict__ Q, const float* __restrict__ K, const float* __restrict__ V,
    const unsigned short* __restrict__ Wf,
    float* __restrict__ Qt, float* __restrict__ Kt, unsigned short* __restrict__ VpT)
{
    __shared__ float red[4][64][16];   // [wave][lane][ct*4+r]  = 16 KB

    int gb = blockIdx.x;
    int job = gb >> 8, tile = gb & 255;
    int r0 = tile * 16;
    const float* X = (job == 0) ? Q : (job == 1) ? K : V;
    int ntct  = (job == 2) ? 4 : 2;
    int pbase = job << 6;
    int t = threadIdx.x, w = t >> 6, l = t & 63;
    int lrow = l & 15, lq = l >> 4;

    const float* xrow = &X[(size_t)(r0 + lrow) * DM + w * 256 + lq * 8];

    floatx4 acc[4];
    #pragma unroll
    for (int i = 0; i < 4; ++i) acc[i] = (floatx4){0.f, 0.f, 0.f, 0.f};

    #pragma unroll
    for (int s = 0; s < 8; ++s) {
        floatx4 g0 = *(const floatx4*)(xrow + s * 32);
        floatx4 g1 = *(const floatx4*)(xrow + s * 32 + 4);
        union { unsigned u[4]; shortx8 v; } ahi, alo;
        split2(g0.x, g0.y, ahi.u[0], alo.u[0]);
        split2(g0.z, g0.w, ahi.u[1], alo.u[1]);
        split2(g1.x, g1.y, ahi.u[2], alo.u[2]);
        split2(g1.z, g1.w, ahi.u[3], alo.u[3]);
        int kc32 = w * 8 + s;
        #pragma unroll
        for (int ct = 0; ct < 4; ++ct) {
            if (ct >= ntct) break;
            int p = pbase + kc32 * ntct + ct;
            const unsigned short* wp = &Wf[(size_t)p * 1024 + l * 8];
            shortx8 bhi = *(const shortx8*)wp;
            shortx8 blo = *(const shortx8*)(wp + 512);
            acc[ct] = __builtin_amdgcn_mfma_f32_16x16x32_bf16(ahi.v, bhi, acc[ct], 0, 0, 0);
            acc[ct] = __builtin_amdgcn_mfma_f32_16x16x32_bf16(ahi.v, blo, acc[ct], 0, 0, 0);
            acc[ct] = __builtin_amdgcn_mfma_f32_16x16x32_bf16(alo.v, bhi, acc[ct], 0, 0, 0);
        }
    }

    #pragma unroll
    for (int ct = 0; ct < 4; ++ct) {
        if (ct >= ntct) break;
        #pragma unroll
        for (int r = 0; r < 4; ++r) red[w][l][ct * 4 + r] = acc[ct][r];
    }
    __syncthreads();

    // wave w sums accumulator register r = w across the 4 k-quarters.
    // C/D layout: (lane, reg r) -> row r0 + (l>>4)*4 + r, col ct*16 + (l&15).
    int row = r0 + lq * 4 + w;
    if (job < 2) {
        float* Y = (job == 0) ? Qt : Kt;
        #pragma unroll
        for (int ct = 0; ct < 2; ++ct) {
            float v = red[0][l][ct * 4 + w] + red[1][l][ct * 4 + w]
                    + red[2][l][ct * 4 + w] + red[3][l][ct * 4 + w];
            Y[(size_t)row * MBITS + ct * 16 + lrow] = v;
        }
    } else {
        int b = row >> 11, j = row & 2047;
        #pragma unroll
        for (int ct = 0; ct < 4; ++ct) {
            float v = red[0][l][ct * 4 + w] + red[1][l][ct * 4 + w]
                    + red[2][l][ct * 4 + w] + red[3][l][ct * 4 + w];
            VpT[(size_t)b * (DH * NB) + (size_t)(ct * 16 + lrow) * NB + j] = f32_to_bf16(v);
        }
    }
}

// ---------------------------------------------------------------------------
// Score pass: tropical min-plus, unnormalized e -> ebuf, per-(row,jc) partials.
// grid (128, 8, 2) x 256. Block = 16 rows x 256 j, thread 4i x 4j.
// ---------------------------------------------------------------------------
template <typename ET>
__global__ __launch_bounds__(256) void trop_score_kernel(
    const float* __restrict__ Qt, const float* __restrict__ Kt,
    const float* __restrict__ temp, float* __restrict__ partial,
    ET* __restrict__ ebuf)
{
    __shared__ float Qs[16][36];
    __shared__ float Ks[256][36];

    int b  = blockIdx.z;
    int jc = blockIdx.y;
    int i0 = blockIdx.x * 16;
    int t  = threadIdx.x;
    int w  = t >> 6, l = t & 63;

    if (t < 128) {
        int row = t >> 3, k4 = t & 7;
        *(floatx4*)&Qs[row][k4 * 4] =
            *(const floatx4*)&Qt[(size_t)(b * NB + i0 + row) * MBITS + k4 * 4];
    }
    #pragma unroll
    for (int u = 0; u < 8; ++u) {
        int flat4 = u * 256 + t;
        int row = flat4 >> 3, k4 = flat4 & 7;
        *(floatx4*)&Ks[row][k4 * 4] =
            *(const floatx4*)&Kt[(size_t)(b * NB + jc * 256 + row) * MBITS + k4 * 4];
    }
    float tv = temp[0];
    float c2 = -(1.0f / log1pf(__expf(tv))) * 1.44269504088896340736f;
    __syncthreads();

    float m[4][4];
    #pragma unroll
    for (int ii = 0; ii < 4; ++ii)
        #pragma unroll
        for (int jj = 0; jj < 4; ++jj) m[ii][jj] = 1e30f;

    #pragma unroll
    for (int k4 = 0; k4 < 8; ++k4) {
        floatx4 q[4], kk[4];
        #pragma unroll
        for (int ii = 0; ii < 4; ++ii) q[ii] = *(const floatx4*)&Qs[w + 4 * ii][k4 * 4];
        #pragma unroll
        for (int jj = 0; jj < 4; ++jj) kk[jj] = *(const floatx4*)&Ks[l + 64 * jj][k4 * 4];
        #pragma unroll
        for (int ii = 0; ii < 4; ++ii)
            #pragma unroll
            for (int jj = 0; jj < 4; ++jj) {
                float a0 = q[ii].x + kk[jj].x;
                float a1 = q[ii].y + kk[jj].y;
                float a2 = q[ii].z + kk[jj].z;
                float a3 = q[ii].w + kk[jj].w;
                m[ii][jj] = fminf(fminf(m[ii][jj], fminf(a0, a1)), fminf(a2, a3));
            }
    }

    float psum[4];
    #pragma unroll
    for (int ii = 0; ii < 4; ++ii) {
        int i = w + 4 * ii;
        float s = 0.f;
        #pragma unroll
        for (int jj = 0; jj < 4; ++jj) {
            int j = l + 64 * jj;
            float e = exp2f(c2 * m[ii][jj]);
            size_t idx = (size_t)(b * NB + i0 + i) * 2048 + jc * 256 + j;
            if (sizeof(ET) == 2) ebuf[idx] = (ET)f32_to_bf16(e);
            else                 ebuf[idx] = (ET)e;
            s += e;
        }
        psum[ii] = s;
    }

    #pragma unroll
    for (int ii = 0; ii < 4; ++ii) {
        float v = psum[ii];
        #pragma unroll
        for (int off = 1; off < 64; off <<= 1) v += __shfl_xor(v, off, 64);
        if (l == 0) partial[((size_t)b * NB + i0 + w + 4 * ii) * 8 + jc] = v;
    }
}

// ---------------------------------------------------------------------------
// Out pass: normalize -> attn f32, MFMA -> out (atomic). grid (128, 8, 2) x 256.
// EBF16: ebuf is bf16 scratch; else ebuf == attn (f32 in-place fallback).
// ---------------------------------------------------------------------------
template <bool EBF16>
__global__ __launch_bounds__(256) void trop_out_kernel(
    const unsigned short* __restrict__ VpT, const float* __restrict__ partial,
    const void* __restrict__ ebuf_in, float* __restrict__ outp, float* __restrict__ attn)
{
    __shared__ unsigned short Vs[64][256];   // B-operand, XOR-swizzled 16B chunks
    __shared__ unsigned short Es[16][264];   // A-operand (unnormalized e, bf16)
    __shared__ float inv_s[16];

    int b  = blockIdx.z;
    int jc = blockIdx.y;
    int i0 = blockIdx.x * 16;
    int t  = threadIdx.x;
    int w  = t >> 6, l = t & 63;

    #pragma unroll
    for (int u = 0; u < 8; ++u) {
        int flat16 = u * 256 + t;
        int h = flat16 >> 5, c = flat16 & 31;
        uint4 g = *(const uint4*)&VpT[(size_t)b * (DH * NB) + (size_t)h * NB + jc * 256 + c * 8];
        *(uint4*)&Vs[h][(c ^ (h & 31)) * 8] = g;
    }
    if (t < 16) {
        float s = 0.f;
        #pragma unroll
        for (int p = 0; p < 8; ++p) s += partial[((size_t)b * NB + i0 + t) * 8 + p];
        inv_s[t] = 1.0f / s;
    }

    if (EBF16) {
        const unsigned short* eb = (const unsigned short*)ebuf_in;
        #pragma unroll
        for (int u = 0; u < 2; ++u) {
            int flat = u * 256 + t;
            int row = flat >> 5, c = flat & 31;
            uint4 g = *(const uint4*)&eb[(size_t)(b * NB + i0 + row) * 2048 + jc * 256 + c * 8];
            *(uint4*)&Es[row][c * 8] = g;
        }
        __syncthreads();
        int row = t >> 4, cb = (t & 15) * 16;
        float iv = inv_s[row];
        #pragma unroll
        for (int h8 = 0; h8 < 2; ++h8) {
            uint4 e8 = *(const uint4*)&Es[row][cb + h8 * 8];
            unsigned uu[4] = {e8.x, e8.y, e8.z, e8.w};
            float f[8];
            #pragma unroll
            for (int z = 0; z < 4; ++z) {
                union { unsigned u; float f; } v0, v1;
                v0.u = uu[z] << 16; v1.u = uu[z] & 0xFFFF0000u;
                f[2 * z] = v0.f * iv; f[2 * z + 1] = v1.f * iv;
            }
            size_t gidx = (size_t)(b * NB + i0 + row) * 2048 + jc * 256 + cb + h8 * 8;
            floatx4 o0; o0.x = f[0]; o0.y = f[1]; o0.z = f[2]; o0.w = f[3];
            floatx4 o1; o1.x = f[4]; o1.y = f[5]; o1.z = f[6]; o1.w = f[7];
            *(floatx4*)&attn[gidx]     = o0;
            *(floatx4*)&attn[gidx + 4] = o1;
        }
    } else {
        __syncthreads();
        #pragma unroll
        for (int u = 0; u < 4; ++u) {
            int flat4 = u * 256 + t;
            int row = flat4 >> 6, c4 = flat4 & 63;
            size_t g = (size_t)(b * NB + i0 + row) * 2048 + jc * 256 + c4 * 4;
            floatx4 e4 = *(const floatx4*)&attn[g];
            float iv = inv_s[row];
            unsigned u0 = (unsigned)f32_to_bf16(e4.x) | ((unsigned)f32_to_bf16(e4.y) << 16);
            unsigned u1 = (unsigned)f32_to_bf16(e4.z) | ((unsigned)f32_to_bf16(e4.w) << 16);
            uint2 pk; pk.x = u0; pk.y = u1;
            *(uint2*)&Es[row][c4 * 4] = pk;
            e4.x *= iv; e4.y *= iv; e4.z *= iv; e4.w *= iv;
            *(floatx4*)&attn[g] = e4;
        }
    }
    __syncthreads();

    floatx4 acc = {0.f, 0.f, 0.f, 0.f};
    #pragma unroll
    for (int kk = 0; kk < 8; ++kk) {
        int mrow = l & 15, q4 = l >> 4;
        shortx8 a = *(const shortx8*)&Es[mrow][kk * 32 + q4 * 8];
        int h = w * 16 + mrow;
        int c = kk * 4 + q4;
        shortx8 bf = *(const shortx8*)&Vs[h][(c ^ (h & 31)) * 8];
        acc = __builtin_amdgcn_mfma_f32_16x16x32_bf16(a, bf, acc, 0, 0, 0);
    }

    #pragma unroll
    for (int r = 0; r < 4; ++r) {
        int irow = (l >> 4) * 4 + r;
        atomicAdd(&outp[(size_t)(b * NB + i0 + irow) * DH + w * 16 + (l & 15)],
                  acc[r] * inv_s[irow]);
    }
}

// ---------------------------------------------------------------------------
extern "C" void kernel_launch(void* const* d_in, const int* in_sizes, int n_in,
                              void* d_out, int out_size, void* d_ws, size_t ws_size,
                              hipStream_t stream) {
    (void)in_sizes; (void)n_in; (void)out_size;
    const float* Q    = (const float*)d_in[0];
    const float* K    = (const float*)d_in[1];
    const float* V    = (const float*)d_in[2];
    const float* Wq   = (const float*)d_in[3];
    const float* Wk   = (const float*)d_in[4];
    const float* Wv   = (const float*)d_in[5];
    const float* temp = (const float*)d_in[6];

    float* outp = (float*)d_out;                 // [2][2048][64]
    float* attn = outp + 2 * 2048 * 64;          // [2][2048][2048]

    char* ws = (char*)d_ws;
    float*          Qt      = (float*)(ws);                       // 512 KB
    float*          Kt      = (float*)(ws + 524288);              // 512 KB
    float*          partial = (float*)(ws + 1048576);             // 128 KB
    unsigned short* Wf      = (unsigned short*)(ws + 1179648);    // 512 KB
    unsigned short* VpT     = (unsigned short*)(ws + 1703936);    // 512 KB
    unsigned short* Ebuf    = (unsigned short*)(ws + 2228224);    // 16.7 MB bf16 e
    bool bf16path = ws_size >= (size_t)2228224 + 16777216;

    hipMemsetAsync(d_out, 0, 262144 * sizeof(float), stream);     // out accumulators

    wprep_kernel<<<64, 256, 0, stream>>>(Wq, Wk, Wv, Wf);
    proj_mfma2_kernel<<<768, 256, 0, stream>>>(Q, K, V, Wf, Qt, Kt, VpT);

    if (bf16path) {
        trop_score_kernel<unsigned short><<<dim3(128, 8, 2), 256, 0, stream>>>(
            Qt, Kt, temp, partial, Ebuf);
        trop_out_kernel<true><<<dim3(128, 8, 2), 256, 0, stream>>>(
            VpT, partial, Ebuf, outp, attn);
    } else {
        trop_score_kernel<float><<<dim3(128, 8, 2), 256, 0, stream>>>(
            Qt, Kt, temp, partial, attn);
        trop_out_kernel<false><<<dim3(128, 8, 2), 256, 0, stream>>>(
            VpT, partial, attn, outp, attn);
    }
}